// Round 11
// baseline (954.357 us; speedup 1.0000x reference)
//
#include <hip/hip_runtime.h>
#include <stdint.h>

typedef unsigned short u16;
typedef __attribute__((ext_vector_type(8))) short short8;
typedef __attribute__((ext_vector_type(4))) float f32x4;

#define M_DIM 8192
#define N_DIM 4096
#define K_DIM 4096

// ---------- fp32 -> bf16 (RNE), 8 elems/thread ----------
__device__ inline u16 f32_to_bf16_rne(float f) {
    uint32_t b = __builtin_bit_cast(uint32_t, f);
    b += 0x7fffu + ((b >> 16) & 1u);
    return (u16)(b >> 16);
}

__global__ __launch_bounds__(256)
void cvt_f32_to_bf16_k(const float* __restrict__ in, u16* __restrict__ out, int n_vec8) {
    int stride = gridDim.x * blockDim.x;
    for (int i = blockIdx.x * blockDim.x + threadIdx.x; i < n_vec8; i += stride) {
        const float4* p = reinterpret_cast<const float4*>(in) + 2 * (size_t)i;
        float4 a = p[0];
        float4 b = p[1];
        float v[8] = {a.x, a.y, a.z, a.w, b.x, b.y, b.z, b.w};
        short8 r;
#pragma unroll
        for (int j = 0; j < 8; ++j) r[j] = (short)f32_to_bf16_rne(v[j]);
        *reinterpret_cast<short8*>(out + 8 * (size_t)i) = r;
    }
}

// ---------- 256x256 8-phase bf16 GEMM: 4 waves x 128x128/wave ----------
// A: [M][K] bf16, B: [N][K] bf16 (B^T), C: [M][N] f32
// 256 threads = 4 waves (2M x 2N); per-wave output 128x128; BK=64.
// LDS: [dbuf][mat][half][128*64] bf16 = 128 KiB. Swizzle S(a)=a^(((a>>7)&7)<<4)
// folded into 8 precomputed per-lane base pointers (buf x mat x ks).
// LDS read traffic: 4 waves x (128+128)x64x2B = 128KB/K-tile (was 192KB with
// 8 waves x 128x64) -> per-CU-phase LDS ~470 cyc < MFMA ~620 cyc.
//
// Quadrants per tile: (mh0,k0)(mh1,k0)(mh0,k1)(mh1,k1); 32 MFMA each.
// Reads JIT one phase ahead; counted lgkm drains exactly the prior phase:
//   P1: rd aQ=A(a,mh1,k0) [4]        | st b.{Ah0,Ah1,Bh0,Bh1} | LGKM(4)  | Q(aP,bA,mh0)
//   P2: rd aP=A(a,mh0,k1),bB=B(a,k1) |                        | LGKM(12) | Q(aQ,bA,mh1)
//   P3: rd aQ=A(a,mh1,k1) [4]        |                        | LGKM(4)  | Q(aP,bB,mh0) | VM0
//   P4: rd aP=A(b,mh0,k0),bA=B(b,k0) |                        | LGKM(12) | Q(aQ,bB,mh1)
//   P5: rd aQ=A(b,mh1,k0)            | st (a+2).{4 halves}    | LGKM(4)  | Q(aP,bA,mh0)
//   P6: rd aP=A(b,mh0,k1),bB=B(b,k1) |                        | LGKM(12) | Q(aQ,bA,mh1)
//   P7: rd aQ=A(b,mh1,k1)            |                        | LGKM(4)  | Q(aP,bB,mh0) | VM0
//   P8: rd aP=A(a+2,mh0,k0),bA=B(a+2,k0)                      | LGKM(12) | Q(aQ,bB,mh1)
// Stage WAR (strict rule: region's last read q <= p-2): buf1 last read P7
// (prev iter) -> stage P1 OK; buf0 last read P3 -> stage P5 OK.
// VM0@P3: 16 DMA outstanding = tile b (issued P1, 2+ phases ~1300cyc > 900 HBM);
// published by P3-close BAR, first read P4. VM0@P7 likewise for (a+2), read P8.
// Reg WAR: aP ovw P2 (last use P1), aQ P3 (P2), bA P4 (P2), bB P6 (P4) - all OK.

#define BAR() do { asm volatile("" ::: "memory"); __builtin_amdgcn_s_barrier(); asm volatile("" ::: "memory"); } while (0)
#define LGKM(n) do { asm volatile("s_waitcnt lgkmcnt(" #n ")" ::: "memory"); __builtin_amdgcn_sched_barrier(0); } while (0)
#define WAIT_VM0() asm volatile("s_waitcnt vmcnt(0)" ::: "memory")

// 32 MFMA: 4 m-frags x 8 n-frags at one (mh, ks)
#define QUAD32(AA, BB, MH)                                                        \
    _Pragma("unroll")                                                             \
    for (int m = 0; m < 4; ++m) {                                                 \
        _Pragma("unroll")                                                         \
        for (int n = 0; n < 8; ++n) {                                             \
            acc[(MH) * 4 + m][n] =                                                \
                __builtin_amdgcn_mfma_f32_16x16x32_bf16(                          \
                    AA[m], BB[n], acc[(MH) * 4 + m][n], 0, 0, 0);                 \
        }                                                                         \
    }

// 4 A-frag reads at one ks: base P (ks folded), MHOFF in {0, 8192} bytes
#define READ_A4(AA, P, MHOFF)                                                     \
    _Pragma("unroll")                                                             \
    for (int m = 0; m < 4; ++m) {                                                 \
        AA[m] = *reinterpret_cast<const short8*>((P) + (MHOFF) + m * 2048);       \
    }

// 8 B-frag reads at one ks (whole 128-col half): base P (ks folded)
#define READ_B8(BB, P)                                                            \
    _Pragma("unroll")                                                             \
    for (int n = 0; n < 8; ++n) {                                                 \
        BB[n] = *reinterpret_cast<const short8*>((P) + n * 2048);                 \
    }

__global__ __launch_bounds__(256, 1)
void gemm_8phase(const u16* __restrict__ A, const u16* __restrict__ B,
                 const float* __restrict__ bias, float* __restrict__ C) {
    __shared__ __align__(16) u16 lds[2][2][2][128 * 64];   // 128 KiB

    const int tid  = threadIdx.x;
    const int wave = tid >> 6;      // 0..3
    const int lane = tid & 63;

    // T1: XCD-aware bijective swizzle (nwg=512, 512%8==0)
    const uint32_t wg = (blockIdx.x & 7u) * 64u + (blockIdx.x >> 3);
    const int bx = (int)(wg % (N_DIM / 256));
    const int by = (int)(wg / (N_DIM / 256));
    const int brow = by * 256;
    const int bcol = bx * 256;

    const int wr = wave >> 1;   // 0..1 -> 128 output rows
    const int wc = wave & 1;    // 0..1 -> 128 output cols

    // staging: half-tile = 128x64 bf16 = 1024 chunks x 16B; 4 chunks/lane.
    // physical chunk cp (linear gload_lds dest) holds LOGICAL cl = cp^((cp>>3)&7)
    uint32_t sr[4], sc[4];
#pragma unroll
    for (int j = 0; j < 4; ++j) {
        const uint32_t cp = (uint32_t)(wave * 64 + lane) + j * 256u;
        const uint32_t cl = cp ^ ((cp >> 3) & 7u);
        sr[j] = cl >> 3;
        sc[j] = (cl & 7u) * 8u;
    }

    const u16* pA[2] = { A + (size_t)(brow)       * K_DIM,
                         A + (size_t)(brow + 128) * K_DIM };
    const u16* pB[2] = { B + (size_t)(bcol)       * K_DIM,
                         B + (size_t)(bcol + 128) * K_DIM };

    // precomputed swizzled per-lane ds_read bases (ks folded)
    const uint32_t kb   = (uint32_t)(lane >> 4) * 16u;
    const uint32_t sw   = (uint32_t)(lane & 7) << 4;
    const uint32_t roff = (uint32_t)(lane & 15) * 128u + kb;

    const char* As0 = (const char*)&lds[0][0][wr][0];
    const char* As1 = (const char*)&lds[1][0][wr][0];
    const char* Bs0 = (const char*)&lds[0][1][wc][0];
    const char* Bs1 = (const char*)&lds[1][1][wc][0];

    const char* pA0k0 = As0 + ((roff)       ^ sw);
    const char* pA0k1 = As0 + ((roff + 64u) ^ sw);
    const char* pA1k0 = As1 + ((roff)       ^ sw);
    const char* pA1k1 = As1 + ((roff + 64u) ^ sw);
    const char* pB0k0 = Bs0 + ((roff)       ^ sw);
    const char* pB0k1 = Bs0 + ((roff + 64u) ^ sw);
    const char* pB1k0 = Bs1 + ((roff)       ^ sw);
    const char* pB1k1 = Bs1 + ((roff + 64u) ^ sw);

    auto STAGE = [&](const u16* gbase, u16* lhalf, int k0) {
#pragma unroll
        for (int j = 0; j < 4; ++j) {
            __builtin_amdgcn_global_load_lds(
                (const __attribute__((address_space(1))) uint32_t*)(gbase + (size_t)sr[j] * K_DIM + k0 + sc[j]),
                (__attribute__((address_space(3))) uint32_t*)(lhalf + wave * 512 + j * 2048), 16, 0, 0);
        }
    };

    f32x4 acc[8][8];
#pragma unroll
    for (int m = 0; m < 8; ++m)
#pragma unroll
        for (int n = 0; n < 8; ++n) acc[m][n] = (f32x4){0.f, 0.f, 0.f, 0.f};

    short8 aP[4], aQ[4], bA[8], bB[8];

    // ---- prologue: tile a=0 (buf0, 4 halves); vm(0); pre-read R(P1) ----
    STAGE(pA[0], &lds[0][0][0][0], 0);
    STAGE(pA[1], &lds[0][0][1][0], 0);
    STAGE(pB[0], &lds[0][1][0][0], 0);
    STAGE(pB[1], &lds[0][1][1][0], 0);
    WAIT_VM0();
    BAR();
    READ_A4(aP, pA0k0, 0);    // A(a, mh0, k0)
    READ_B8(bA, pB0k0);       // B(a, k0)

    // ---- main loop: iter i computes tiles a=2i (buf0), b=2i+1 (buf1) ----
    for (int i = 0; i < K_DIM / 128; ++i) {
        const int k_b  = (2 * i + 1) * 64;                   // <= 4032
        const int k_a2 = ((2 * i + 2) * 64) & (K_DIM - 1);   // wraps harmlessly last iter

        // P1: rd aQ (4) | stage tile b (all 4 halves) | Q(aP,bA,mh0)
        READ_A4(aQ, pA0k0, 8192);
        STAGE(pA[0], &lds[1][0][0][0], k_b);
        STAGE(pA[1], &lds[1][0][1][0], k_b);
        STAGE(pB[0], &lds[1][1][0][0], k_b);
        STAGE(pB[1], &lds[1][1][1][0], k_b);
        BAR(); LGKM(4);
        __builtin_amdgcn_s_setprio(1);
        QUAD32(aP, bA, 0);
        __builtin_amdgcn_s_setprio(0);
        BAR();

        // P2: rd aP, bB (12) | Q(aQ,bA,mh1)
        READ_A4(aP, pA0k1, 0);
        READ_B8(bB, pB0k1);
        BAR(); LGKM(12);
        __builtin_amdgcn_s_setprio(1);
        QUAD32(aQ, bA, 1);
        __builtin_amdgcn_s_setprio(0);
        BAR();

        // P3: rd aQ (4) | Q(aP,bB,mh0) | vm(0): publish tile b
        READ_A4(aQ, pA0k1, 8192);
        BAR(); LGKM(4);
        __builtin_amdgcn_s_setprio(1);
        QUAD32(aP, bB, 0);
        __builtin_amdgcn_s_setprio(0);
        WAIT_VM0();
        BAR();

        // P4: rd aP, bA from buf1 (12) | Q(aQ,bB,mh1)
        READ_A4(aP, pA1k0, 0);
        READ_B8(bA, pB1k0);
        BAR(); LGKM(12);
        __builtin_amdgcn_s_setprio(1);
        QUAD32(aQ, bB, 1);
        __builtin_amdgcn_s_setprio(0);
        BAR();

        // P5: rd aQ (4) | stage tile a+2 (all 4 halves) | Q(aP,bA,mh0)
        READ_A4(aQ, pA1k0, 8192);
        STAGE(pA[0], &lds[0][0][0][0], k_a2);
        STAGE(pA[1], &lds[0][0][1][0], k_a2);
        STAGE(pB[0], &lds[0][1][0][0], k_a2);
        STAGE(pB[1], &lds[0][1][1][0], k_a2);
        BAR(); LGKM(4);
        __builtin_amdgcn_s_setprio(1);
        QUAD32(aP, bA, 0);
        __builtin_amdgcn_s_setprio(0);
        BAR();

        // P6: rd aP, bB (12) | Q(aQ,bA,mh1)
        READ_A4(aP, pA1k1, 0);
        READ_B8(bB, pB1k1);
        BAR(); LGKM(12);
        __builtin_amdgcn_s_setprio(1);
        QUAD32(aQ, bA, 1);
        __builtin_amdgcn_s_setprio(0);
        BAR();

        // P7: rd aQ (4) | Q(aP,bB,mh0) | vm(0): publish tile a+2
        READ_A4(aQ, pA1k1, 8192);
        BAR(); LGKM(4);
        __builtin_amdgcn_s_setprio(1);
        QUAD32(aP, bB, 0);
        __builtin_amdgcn_s_setprio(0);
        WAIT_VM0();
        BAR();

        // P8: rd aP, bA from buf0=(a+2) (12) | Q(aQ,bB,mh1)
        READ_A4(aP, pA0k0, 0);
        READ_B8(bA, pB0k0);
        BAR(); LGKM(12);
        __builtin_amdgcn_s_setprio(1);
        QUAD32(aQ, bB, 1);
        __builtin_amdgcn_s_setprio(0);
        BAR();
    }

    WAIT_VM0();    // drain wrapped prefetches
    LGKM(0);       // drain dangling P8 reads before epilogue reuses regs

    // ---- epilogue: C/D layout col=lane&15, row=(lane>>4)*4+j ----
    const int orow = brow + wr * 128 + (lane >> 4) * 4;
    const int ocol = bcol + wc * 128 + (lane & 15);
#pragma unroll
    for (int n = 0; n < 8; ++n) {
        const int c = ocol + n * 16;
        const float bv = bias[c];
#pragma unroll
        for (int m = 0; m < 8; ++m) {
#pragma unroll
            for (int j = 0; j < 4; ++j) {
                C[(size_t)(orow + m * 16 + j) * N_DIM + c] = acc[m][n][j] + bv;
            }
        }
    }
}

// ---------- fallback (ws too small): correct, slow fp32 ----------
__global__ __launch_bounds__(256)
void gemm_f32_naive(const float* __restrict__ x, const float* __restrict__ w,
                    const float* __restrict__ bias, float* __restrict__ out) {
    const size_t total = (size_t)M_DIM * N_DIM;
    const size_t stride = (size_t)gridDim.x * blockDim.x;
    for (size_t idx = (size_t)blockIdx.x * blockDim.x + threadIdx.x; idx < total; idx += stride) {
        const int b = (int)(idx / N_DIM);
        const int o = (int)(idx % N_DIM);
        const float* xr = x + (size_t)b * K_DIM;
        const float* wr = w + (size_t)o * K_DIM;
        float s = bias[o];
        for (int k = 0; k < K_DIM; ++k) s = fmaf(xr[k], wr[k], s);
        out[idx] = s;
    }
}

extern "C" void kernel_launch(void* const* d_in, const int* in_sizes, int n_in,
                              void* d_out, int out_size, void* d_ws, size_t ws_size,
                              hipStream_t stream) {
    const float* x    = (const float*)d_in[0];
    const float* w    = (const float*)d_in[1];
    const float* bias = (const float*)d_in[2];
    float* out = (float*)d_out;

    const size_t xb_elems = (size_t)M_DIM * K_DIM;
    const size_t wb_elems = (size_t)N_DIM * K_DIM;
    const size_t need = (xb_elems + wb_elems) * sizeof(u16);

    if (ws_size >= need) {
        u16* xb = (u16*)d_ws;
        u16* wb = xb + xb_elems;
        cvt_f32_to_bf16_k<<<2048, 256, 0, stream>>>(x, xb, (int)(xb_elems / 8));
        cvt_f32_to_bf16_k<<<2048, 256, 0, stream>>>(w, wb, (int)(wb_elems / 8));
        const int nwg = (M_DIM / 256) * (N_DIM / 256);   // 32*16 = 512
        gemm_8phase<<<nwg, 256, 0, stream>>>(xb, wb, bias, out);
    } else {
        gemm_f32_naive<<<4096, 256, 0, stream>>>(x, w, bias, out);
    }
}

// Round 12
// 278.334 us; speedup vs baseline: 3.4288x; 3.4288x over previous
//
#include <hip/hip_runtime.h>
#include <stdint.h>

typedef unsigned short u16;
typedef __attribute__((ext_vector_type(8))) short short8;
typedef __attribute__((ext_vector_type(4))) float f32x4;

#define M_DIM 8192
#define N_DIM 4096
#define K_DIM 4096

// ---------- fp32 -> bf16 (RNE), 8 elems/thread ----------
__device__ inline u16 f32_to_bf16_rne(float f) {
    uint32_t b = __builtin_bit_cast(uint32_t, f);
    b += 0x7fffu + ((b >> 16) & 1u);
    return (u16)(b >> 16);
}

__global__ __launch_bounds__(256)
void cvt_f32_to_bf16_k(const float* __restrict__ in, u16* __restrict__ out, int n_vec8) {
    int stride = gridDim.x * blockDim.x;
    for (int i = blockIdx.x * blockDim.x + threadIdx.x; i < n_vec8; i += stride) {
        const float4* p = reinterpret_cast<const float4*>(in) + 2 * (size_t)i;
        float4 a = p[0];
        float4 b = p[1];
        float v[8] = {a.x, a.y, a.z, a.w, b.x, b.y, b.z, b.w};
        short8 r;
#pragma unroll
        for (int j = 0; j < 8; ++j) r[j] = (short)f32_to_bf16_rne(v[j]);
        *reinterpret_cast<short8*>(out + 8 * (size_t)i) = r;
    }
}

// ---------- 256x256 bf16 GEMM: 4 merged phases/iter (r9 sched, half barriers) ----------
// A: [M][K] bf16, B: [N][K] bf16 (B^T), C: [M][N] f32
// 512 threads = 8 waves (2M x 4N); per-wave 128x64; BK=64; 2 K-tiles/iter.
// LDS: [dbuf][mat][half][128*64] bf16 = 128 KiB. Swizzle S(a)=a^(((a>>7)&7)<<4)
// folded into 8 precomputed per-lane base pointers.
//
// Merged phase = two 16-MFMA clusters with a counted MID-phase lgkm instead of
// a barrier pair. Issues: S1 at phase start (feeds this phase's cluster 2),
// S2 AFTER cluster 1 (feeds next phase's cluster 1; S2 overwrites cluster-1
// operand regs, so it must follow quad1 issue).
//   M1 (tile a, mh0): S1={aB<-a.mh0k1, bB<-a.k1}(8)  S2={aA<-a.mh1k0}(4)
//       stage buf1.A<-b.Ah0,Ah1 | open LGKM(8) | mid LGKM(4) | VM(0)@end
//   M2 (tile a, mh1): S1={aB<-a.mh1k1}(4)  S2={aA<-b.mh0k0, bA<-b.k0}(8)
//       stage buf0.B<-(a+2).Bh0,Bh1 | open LGKM(4) | mid LGKM(8)
//   M3 (tile b, mh0): S1={aB<-b.mh0k1, bB<-b.k1}(8)  S2={aA<-b.mh1k0}(4)
//       stage buf0.A<-(a+2).Ah0,Ah1 | open LGKM(8) | mid LGKM(4) | VM(0)@end
//   M4 (tile b, mh1): S1={aB<-b.mh1k1}(4)  S2={aA<-(a+2).mh0k0, bA<-(a+2).k0}(8)
//       stage buf1.B<-(b+2).Bh0,Bh1 | open LGKM(4) | mid LGKM(8)
// lgkm ledger (steady): M1-open out=16 drain M4p-S2; M1-mid out=12 drain S1;
//   M2-open out=8 drain M1-S2; M2-mid out=12 drain M2-S1; M3/M4 mirror. All
//   counted waits drain exactly the set the following cluster consumes.
// Stage WAR (strict): buf1.A last drain M4-mid -> stage M1_next; buf0.B last
//   drain M1-mid -> stage M2; buf0.A last drain M2-mid -> stage M3; buf1.B
//   last drain M3-mid -> stage M4. Each stage >=1 close-BAR after drain.
// vm: VM(0)@M1-end publishes tile b (out = M4p:4 + M1:4); first read-issue
//   M2-mid (after M1-close BAR). VM(0)@M3-end publishes a+2 likewise.
// Reg WAR: aA ovw at S2 after quad1 issue; aB ovw at S1 after prev quad2
//   issue (pre-barrier); bA ovw M2/M4-S2 after quad1; bB ovw M1/M3-S1. All OK.

#define BAR() do { asm volatile("" ::: "memory"); __builtin_amdgcn_s_barrier(); asm volatile("" ::: "memory"); } while (0)
#define LGKM(n) do { asm volatile("s_waitcnt lgkmcnt(" #n ")" ::: "memory"); __builtin_amdgcn_sched_barrier(0); } while (0)
#define WAIT_VM4() asm volatile("s_waitcnt vmcnt(4)" ::: "memory")
#define WAIT_VM0() asm volatile("s_waitcnt vmcnt(0)" ::: "memory")

// 16 MFMA: 4 m-frags x 4 n-frags at one (mh, ks)
#define QUAD16(AA, BB, MH)                                                        \
    _Pragma("unroll")                                                             \
    for (int m = 0; m < 4; ++m) {                                                 \
        _Pragma("unroll")                                                         \
        for (int n = 0; n < 4; ++n) {                                             \
            acc[(MH) * 4 + m][n] =                                                \
                __builtin_amdgcn_mfma_f32_16x16x32_bf16(                          \
                    AA[m], BB[n], acc[(MH) * 4 + m][n], 0, 0, 0);                 \
        }                                                                         \
    }

#define READ_A4(AA, P, MHOFF)                                                     \
    _Pragma("unroll")                                                             \
    for (int m = 0; m < 4; ++m) {                                                 \
        AA[m] = *reinterpret_cast<const short8*>((P) + (MHOFF) + m * 2048);       \
    }

#define READ_B4(BB, P)                                                            \
    _Pragma("unroll")                                                             \
    for (int n = 0; n < 4; ++n) {                                                 \
        BB[n] = *reinterpret_cast<const short8*>((P) + n * 2048);                 \
    }

__global__ __launch_bounds__(512, 2)
void gemm_8phase(const u16* __restrict__ A, const u16* __restrict__ B,
                 const float* __restrict__ bias, float* __restrict__ C) {
    __shared__ __align__(16) u16 lds[2][2][2][128 * 64];   // 128 KiB

    const int tid  = threadIdx.x;
    const int wave = tid >> 6;
    const int lane = tid & 63;

    // T1: XCD-aware bijective swizzle (nwg=512, 512%8==0)
    const uint32_t wg = (blockIdx.x & 7u) * 64u + (blockIdx.x >> 3);
    const int bx = (int)(wg % (N_DIM / 256));
    const int by = (int)(wg / (N_DIM / 256));
    const int brow = by * 256;
    const int bcol = bx * 256;

    const int wr = wave >> 2;   // 0..1 -> 128 output rows each
    const int wc = wave & 3;    // 0..3 -> 64 output cols each

    // staging: physical chunk cp (linear gload_lds dest) holds LOGICAL chunk
    // cl = cp ^ ((cp>>3)&7)  (16B-chunk form of S; involution)
    const uint32_t cp0 = (uint32_t)(wave * 64 + lane);
    const uint32_t cp1 = cp0 + 512u;
    const uint32_t cl0 = cp0 ^ ((cp0 >> 3) & 7u);
    const uint32_t cl1 = cp1 ^ ((cp1 >> 3) & 7u);
    const uint32_t sr0 = cl0 >> 3, sc0 = (cl0 & 7u) * 8u;
    const uint32_t sr1 = cl1 >> 3, sc1 = (cl1 & 7u) * 8u;

    const u16* pA[2] = { A + (size_t)(brow)       * K_DIM,
                         A + (size_t)(brow + 128) * K_DIM };
    const u16* pB[2] = { B + (size_t)(bcol)       * K_DIM,
                         B + (size_t)(bcol + 128) * K_DIM };

    // precomputed swizzled per-lane ds_read bases (ks folded)
    const uint32_t kb   = (uint32_t)(lane >> 4) * 16u;
    const uint32_t sw   = (uint32_t)(lane & 7) << 4;
    const uint32_t aoff = (uint32_t)(lane & 15) * 128u + kb;
    const uint32_t boff = (uint32_t)(wc & 1) * 8192u + (uint32_t)(lane & 15) * 128u + kb;

    const char* As0 = (const char*)&lds[0][0][wr][0];
    const char* As1 = (const char*)&lds[1][0][wr][0];
    const char* Bs0 = (const char*)&lds[0][1][wc >> 1][0];
    const char* Bs1 = (const char*)&lds[1][1][wc >> 1][0];

    const char* pA0k0 = As0 + ((aoff)        ^ sw);
    const char* pA0k1 = As0 + ((aoff + 64u)  ^ sw);
    const char* pA1k0 = As1 + ((aoff)        ^ sw);
    const char* pA1k1 = As1 + ((aoff + 64u)  ^ sw);
    const char* pB0k0 = Bs0 + ((boff)        ^ sw);
    const char* pB0k1 = Bs0 + ((boff + 64u)  ^ sw);
    const char* pB1k0 = Bs1 + ((boff)        ^ sw);
    const char* pB1k1 = Bs1 + ((boff + 64u)  ^ sw);

    auto STAGE = [&](const u16* gbase, u16* lhalf, int k0) {
        __builtin_amdgcn_global_load_lds(
            (const __attribute__((address_space(1))) uint32_t*)(gbase + (size_t)sr0 * K_DIM + k0 + sc0),
            (__attribute__((address_space(3))) uint32_t*)(lhalf + wave * 512), 16, 0, 0);
        __builtin_amdgcn_global_load_lds(
            (const __attribute__((address_space(1))) uint32_t*)(gbase + (size_t)sr1 * K_DIM + k0 + sc1),
            (__attribute__((address_space(3))) uint32_t*)(lhalf + 4096 + wave * 512), 16, 0, 0);
    };

    f32x4 acc[8][4];
#pragma unroll
    for (int m = 0; m < 8; ++m)
#pragma unroll
        for (int n = 0; n < 4; ++n) acc[m][n] = (f32x4){0.f, 0.f, 0.f, 0.f};

    short8 aA[4], aB[4], bA[4], bB[4];

    // ---- prologue: tile a=0 (8 DMA) + buf1.B <- tile1.B (4 DMA); VM(4);
    //      pre-issue "M4p-S2" reads {aA<-a.mh0k0, bA<-a.k0} (8) ----
    STAGE(pA[0], &lds[0][0][0][0], 0);
    STAGE(pA[1], &lds[0][0][1][0], 0);
    STAGE(pB[0], &lds[0][1][0][0], 0);
    STAGE(pB[1], &lds[0][1][1][0], 0);
    STAGE(pB[0], &lds[1][1][0][0], 64);
    STAGE(pB[1], &lds[1][1][1][0], 64);
    WAIT_VM4();   // tile a landed; b.B (4) in flight
    BAR();
    READ_A4(aA, pA0k0, 0);
    READ_B4(bA, pB0k0);

    // ---- main loop: iter i computes tiles a=2i (buf0), b=2i+1 (buf1) ----
    for (int i = 0; i < K_DIM / 128; ++i) {
        const int k_b  = (2 * i + 1) * 64;                   // <= 4032
        const int k_a2 = ((2 * i + 2) * 64) & (K_DIM - 1);   // wraps harmlessly last iter
        const int k_b2 = ((2 * i + 3) * 64) & (K_DIM - 1);

        // M1 (tile a, mh0): S1 | stage b.Ah0+Ah1 | Q(aA,bA,0) | S2 | Q(aB,bB,0) | VM0
        READ_A4(aB, pA0k1, 0);           // S1: a.mh0k1
        READ_B4(bB, pB0k1);              // S1: a.k1
        STAGE(pA[0], &lds[1][0][0][0], k_b);
        STAGE(pA[1], &lds[1][0][1][0], k_b);
        BAR(); LGKM(8);                  // drain M4p-S2 -> aA,bA ready
        __builtin_amdgcn_s_setprio(1);
        QUAD16(aA, bA, 0);
        __builtin_amdgcn_s_setprio(0);
        READ_A4(aA, pA0k0, 8192);        // S2: a.mh1k0
        LGKM(4);                         // drain S1 -> aB,bB ready
        __builtin_amdgcn_s_setprio(1);
        QUAD16(aB, bB, 0);
        __builtin_amdgcn_s_setprio(0);
        WAIT_VM0();                      // publish tile b (M4p:4 + M1:4 drained)
        BAR();

        // M2 (tile a, mh1): S1 | stage (a+2).Bh0+Bh1 | Q(aA,bA,1) | S2 | Q(aB,bB,1)
        READ_A4(aB, pA0k1, 8192);        // S1: a.mh1k1
        STAGE(pB[0], &lds[0][1][0][0], k_a2);
        STAGE(pB[1], &lds[0][1][1][0], k_a2);
        BAR(); LGKM(4);                  // drain M1-S2 -> aA=(a,mh1k0); bA=(a,k0) live
        __builtin_amdgcn_s_setprio(1);
        QUAD16(aA, bA, 1);
        __builtin_amdgcn_s_setprio(0);
        READ_A4(aA, pA1k0, 0);           // S2: b.mh0k0
        READ_B4(bA, pB1k0);              // S2: b.k0
        LGKM(8);                         // drain M2-S1 -> aB=(a,mh1k1); bB=(a,k1) live
        __builtin_amdgcn_s_setprio(1);
        QUAD16(aB, bB, 1);
        __builtin_amdgcn_s_setprio(0);
        BAR();

        // M3 (tile b, mh0): S1 | stage (a+2).Ah0+Ah1 | Q(aA,bA,0) | S2 | Q(aB,bB,0) | VM0
        READ_A4(aB, pA1k1, 0);           // S1: b.mh0k1
        READ_B4(bB, pB1k1);              // S1: b.k1
        STAGE(pA[0], &lds[0][0][0][0], k_a2);
        STAGE(pA[1], &lds[0][0][1][0], k_a2);
        BAR(); LGKM(8);                  // drain M2-S2 -> aA=(b,mh0k0), bA=(b,k0)
        __builtin_amdgcn_s_setprio(1);
        QUAD16(aA, bA, 0);
        __builtin_amdgcn_s_setprio(0);
        READ_A4(aA, pA1k0, 8192);        // S2: b.mh1k0
        LGKM(4);                         // drain S1
        __builtin_amdgcn_s_setprio(1);
        QUAD16(aB, bB, 0);
        __builtin_amdgcn_s_setprio(0);
        WAIT_VM0();                      // publish tile a+2 (M2:4 + M3:4 drained)
        BAR();

        // M4 (tile b, mh1): S1 | stage (b+2).Bh0+Bh1 | Q(aA,bA,1) | S2 | Q(aB,bB,1)
        READ_A4(aB, pA1k1, 8192);        // S1: b.mh1k1
        STAGE(pB[0], &lds[1][1][0][0], k_b2);
        STAGE(pB[1], &lds[1][1][1][0], k_b2);
        BAR(); LGKM(4);                  // drain M3-S2 -> aA=(b,mh1k0); bA=(b,k0) live
        __builtin_amdgcn_s_setprio(1);
        QUAD16(aA, bA, 1);
        __builtin_amdgcn_s_setprio(0);
        READ_A4(aA, pA0k0, 0);           // S2: (a+2).mh0k0
        READ_B4(bA, pB0k0);              // S2: (a+2).k0
        LGKM(8);                         // drain M4-S1 -> aB=(b,mh1k1); bB=(b,k1) live
        __builtin_amdgcn_s_setprio(1);
        QUAD16(aB, bB, 1);
        __builtin_amdgcn_s_setprio(0);
        BAR();
    }

    WAIT_VM0();    // drain wrapped prefetches
    LGKM(0);       // drain dangling M4-S2 reads before epilogue reuses regs

    // ---- epilogue: C/D layout col=lane&15, row=(lane>>4)*4+j ----
    const int orow = brow + wr * 128 + (lane >> 4) * 4;
    const int ocol = bcol + wc * 64 + (lane & 15);
#pragma unroll
    for (int n = 0; n < 4; ++n) {
        const int c = ocol + n * 16;
        const float bv = bias[c];
#pragma unroll
        for (int m = 0; m < 8; ++m) {
#pragma unroll
            for (int j = 0; j < 4; ++j) {
                C[(size_t)(orow + m * 16 + j) * N_DIM + c] = acc[m][n][j] + bv;
            }
        }
    }
}

// ---------- fallback (ws too small): correct, slow fp32 ----------
__global__ __launch_bounds__(256)
void gemm_f32_naive(const float* __restrict__ x, const float* __restrict__ w,
                    const float* __restrict__ bias, float* __restrict__ out) {
    const size_t total = (size_t)M_DIM * N_DIM;
    const size_t stride = (size_t)gridDim.x * blockDim.x;
    for (size_t idx = (size_t)blockIdx.x * blockDim.x + threadIdx.x; idx < total; idx += stride) {
        const int b = (int)(idx / N_DIM);
        const int o = (int)(idx % N_DIM);
        const float* xr = x + (size_t)b * K_DIM;
        const float* wr = w + (size_t)o * K_DIM;
        float s = bias[o];
        for (int k = 0; k < K_DIM; ++k) s = fmaf(xr[k], wr[k], s);
        out[idx] = s;
    }
}

extern "C" void kernel_launch(void* const* d_in, const int* in_sizes, int n_in,
                              void* d_out, int out_size, void* d_ws, size_t ws_size,
                              hipStream_t stream) {
    const float* x    = (const float*)d_in[0];
    const float* w    = (const float*)d_in[1];
    const float* bias = (const float*)d_in[2];
    float* out = (float*)d_out;

    const size_t xb_elems = (size_t)M_DIM * K_DIM;
    const size_t wb_elems = (size_t)N_DIM * K_DIM;
    const size_t need = (xb_elems + wb_elems) * sizeof(u16);

    if (ws_size >= need) {
        u16* xb = (u16*)d_ws;
        u16* wb = xb + xb_elems;
        cvt_f32_to_bf16_k<<<2048, 256, 0, stream>>>(x, xb, (int)(xb_elems / 8));
        cvt_f32_to_bf16_k<<<2048, 256, 0, stream>>>(w, wb, (int)(wb_elems / 8));
        const int nwg = (M_DIM / 256) * (N_DIM / 256);   // 32*16 = 512
        gemm_8phase<<<nwg, 512, 0, stream>>>(xb, wb, bias, out);
    } else {
        gemm_f32_naive<<<4096, 256, 0, stream>>>(x, w, bias, out);
    }
}